// Round 8
// baseline (3768.638 us; speedup 1.0000x reference)
//
#include <hip/hip_runtime.h>

// VanillaRNN: BATCH=1024, SEQ=512, HID=512, OUT=10
// h <- tanh(W_hh @ h + W_hx x_t + b_h), 512 steps, then y = W_yh h + b_y.
//
// Round 8: CU-local (zero inter-WG comm), 64 WGs x 256 thr = 4 waves,
// 1 wave/SIMD -> 512 unified regs/lane. R7 post-mortem: compiler's arch
// demand at this shape is 256 regs, so 352 pinned AGPRs spilled (608>512).
// Ledger-correct split (pipes overlap; per-CU-step targets ~2500 cyc each):
//   kk 0..6  (K=224): 56 f16x8 frags pinned to AGPRs (224 regs; 224+256<512)
//   kk 7..10 (K=128): LDS WL (128 KB -> bf 64 + WL 128 = 192 KB/step, 2314 cyc)
//   kk 11..15(K=160): streamed from L2 each step (160 KB, 2926 cyc, own pipe)
// MFMA floor 512/CU-step x 4.85 cyc = 2484 cyc. h (16 KB) in LDS in place,
// 2 barriers/step. Arithmetic identical to R3-R7 (absmax 9.77e-4).
//
// ws: [0,1MB) hG (final h, frag-blocked) | [2MB,2.5MB) W A-frags.

#define BATCH 1024
#define SEQT  512
#define HID   512
#define OUTD  10
#define KA    7    // kk-blocks (of K=32) in AGPRs
#define KL    4    // kk-blocks in LDS (kk 7..10); kk 11..15 streamed

typedef _Float16 f16;
typedef _Float16 f16x8 __attribute__((ext_vector_type(8)));
typedef _Float16 f16x4 __attribute__((ext_vector_type(4)));
typedef float    f32x4 __attribute__((ext_vector_type(4)));

// W_hh fp32 [H][H] -> fp16 A-fragment layout:
// entry (G*16+kk)*64+lane = f16x8 of A[m][k],
// m = G*16+(lane&15), k = kk*32+((lane>>4)&3)*8+j.  (G = 16-row tile, 0..31)
__global__ void wconv_kernel(const float* __restrict__ Whh, f16* __restrict__ frag) {
    int id = blockIdx.x * blockDim.x + threadIdx.x;   // 0..32767
    int lane = id & 63;
    int kk   = (id >> 6) & 15;
    int G    = id >> 10;
    int m = G * 16 + (lane & 15);
    int k = kk * 32 + ((lane >> 4) & 3) * 8;
    const float* src = Whh + (size_t)m * HID + k;
    f16x8 v;
#pragma unroll
    for (int j = 0; j < 8; ++j) v[j] = (f16)src[j];
    *(f16x8*)(frag + (size_t)id * 8) = v;
}

__device__ __forceinline__ float fast_tanh(float v) {
    v = fminf(fmaxf(v, -15.f), 15.f);
    float e = __expf(2.f * v);
    return (e - 1.f) * __builtin_amdgcn_rcpf(e + 1.f);
}

__global__ __launch_bounds__(256, 1)
void rnn_cu(
    const f16* __restrict__ frag,   // W_hh A-frags (all 16 kk-blocks)
    f16* __restrict__ hG,           // final h, frag-blocked
    const float* __restrict__ x,    // [B][T]
    const float* __restrict__ Whx,  // [H]
    const float* __restrict__ bh)   // [H]
{
    __shared__ f16 HB[8192];        // h, B-frag layout, 16 KB (low ds offsets)
    __shared__ f16 WL[65536];       // W A-frags kk 7..10, 128 KB

    const int tid  = threadIdx.x;
    const int w    = tid >> 6;      // wave: rows [w*128, +128) = G w*8..w*8+7
    const int lane = tid & 63;
    const int n    = lane & 15;
    const int q    = lane >> 4;
    const int bg   = blockIdx.x;    // batch cols [bg*16, +16)

    // ---- h(0) = 0 ----
    {
        f16x8 z;
#pragma unroll
        for (int j = 0; j < 8; ++j) z[j] = (f16)0.f;
        *(f16x8*)&HB[tid * 32]      = z;
        *(f16x8*)&HB[tid * 32 + 8]  = z;
        *(f16x8*)&HB[tid * 32 + 16] = z;
        *(f16x8*)&HB[tid * 32 + 24] = z;
    }

    const f16x8* A = (const f16x8*)frag;

    // ---- stage LDS W (kk 7..10): wave w writes its 32 frags ----
#pragma unroll
    for (int mt = 0; mt < 8; ++mt)
#pragma unroll
        for (int kkl = 0; kkl < KL; ++kkl) {
            int G = w * 8 + mt;
            *(f16x8*)&WL[(size_t)((G * 4 + kkl) * 64 + lane) * 8] =
                A[(size_t)(G * 16 + (KA + kkl)) * 64 + lane];
        }

    // ---- AGPR W (kk 0..6): 56 frags = 224 AGPRs/lane, virtually pinned.
    // "+a" = non-rematerializable AGPR-class def the allocator keeps live.
    // 224 AGPR + <=288 arch fits the 512 unified budget (R7's 352 did not).
    f16x8 Wr[KA * 8];
#pragma unroll
    for (int kk = 0; kk < KA; ++kk)
#pragma unroll
        for (int mt = 0; mt < 8; ++mt)
            Wr[kk * 8 + mt] = A[(size_t)((w * 8 + mt) * 16 + kk) * 64 + lane];
#pragma unroll
    for (int i = 0; i < KA * 8; ++i)
        asm volatile("" : "+a"(Wr[i]));

    __syncthreads();

    const int b = bg * 16 + n;
    const float* xp = x + (size_t)b * SEQT;

#pragma unroll 1
    for (int s = 0; s < SEQT; ++s) {
        float xv = xp[s];

        // Laundered stream pointer (keeps per-step loads, blocks hoisting).
        const f16x8* Ap = A;
        asm volatile("" : "+v"(Ap));

        f32x4 acc[8] = {{0,0,0,0},{0,0,0,0},{0,0,0,0},{0,0,0,0},
                        {0,0,0,0},{0,0,0,0},{0,0,0,0},{0,0,0,0}};

        // ---- phase 1: kk 0..6 from AGPRs ----
#pragma unroll
        for (int kk = 0; kk < KA; ++kk) {
            f16x8 bf = *(const f16x8*)&HB[(kk * 64 + lane) * 8];
#pragma unroll
            for (int mt = 0; mt < 8; ++mt)
                acc[mt] = __builtin_amdgcn_mfma_f32_16x16x32_f16(
                    Wr[kk * 8 + mt], bf, acc[mt], 0, 0, 0);
        }

        // ---- phase 2: kk 7..10 from LDS ----
#pragma unroll
        for (int kkl = 0; kkl < KL; ++kkl) {
            f16x8 bf = *(const f16x8*)&HB[((KA + kkl) * 64 + lane) * 8];
#pragma unroll
            for (int mt = 0; mt < 8; ++mt) {
                int G = w * 8 + mt;
                f16x8 a = *(const f16x8*)&WL[(size_t)((G * 4 + kkl) * 64 + lane) * 8];
                acc[mt] = __builtin_amdgcn_mfma_f32_16x16x32_f16(a, bf, acc[mt], 0, 0, 0);
            }
        }

        // ---- phase 3: kk 11..15 streamed from L2 (compiler pipelines the
        // loads ahead of the MFMAs within the free ~280 arch regs) ----
#pragma unroll
        for (int kks = KA + KL; kks < 16; ++kks) {
            f16x8 bf = *(const f16x8*)&HB[(kks * 64 + lane) * 8];
#pragma unroll
            for (int mt = 0; mt < 8; ++mt) {
                f16x8 a = Ap[(size_t)((w * 8 + mt) * 16 + kks) * 64 + lane];
                acc[mt] = __builtin_amdgcn_mfma_f32_16x16x32_f16(a, bf, acc[mt], 0, 0, 0);
            }
        }

        __syncthreads();   // all reads of h(s) done before in-place overwrite

        // Keep Whx/bh loads in-loop (hoisting costs 64 regs -> spill risk).
        const float* wbp = Whx;
        const float* bbp = bh;
        asm volatile("" : "+v"(wbp), "+v"(bbp));

        // ---- epilogue: tanh, write h(s+1) in B-frag layout ----
        // C layout: col n = lane&15, row m = G*16 + q*4 + r.
#pragma unroll
        for (int mt = 0; mt < 8; ++mt) {
            int G  = w * 8 + mt;
            int m0 = G * 16 + q * 4;
            f32x4 whx4 = *(const f32x4*)(wbp + m0);
            f32x4 bh4  = *(const f32x4*)(bbp + m0);
            f16x4 hv;
#pragma unroll
            for (int r = 0; r < 4; ++r) {
                float pre = acc[mt][r] + whx4[r] * xv + bh4[r];
                hv[r] = (f16)fast_tanh(pre);
            }
            int kkd = G >> 1;
            int q2  = (G & 1) * 2 + (q >> 1);
            int j0  = (q & 1) * 4;
            int off = (kkd * 64 + q2 * 16 + n) * 8 + j0;
            if (s < SEQT - 1) {
                *(f16x4*)&HB[off] = hv;
            } else {
                *(f16x4*)(hG + (size_t)(((bg * 16 + kkd) * 64 + q2 * 16 + n) * 8 + j0)) = hv;
            }
        }

        __syncthreads();   // h(s+1) complete before next step's reads
    }
}

// out[b][o] = by[o] + sum_k Wyh[o][k] * h[b][k], h in frag-blocked layout.
__global__ __launch_bounds__(256) void y_kernel(
    const f16* __restrict__ h, const float* __restrict__ Wyh,
    const float* __restrict__ by, float* __restrict__ out)
{
    int id = blockIdx.x * blockDim.x + threadIdx.x;
    if (id >= BATCH * OUTD) return;
    int b = id / OUTD, o = id % OUTD;
    int bg = b >> 4, n = b & 15;
    const float* wrow = Wyh + (size_t)o * HID;
    float s = by[o];
    for (int kk = 0; kk < 16; ++kk)
#pragma unroll
        for (int q2 = 0; q2 < 4; ++q2) {
            f16x8 hv = *(const f16x8*)(h + (size_t)((bg * 16 + kk) * 64 + q2 * 16 + n) * 8);
            const float* wp = wrow + kk * 32 + q2 * 8;
#pragma unroll
            for (int j = 0; j < 8; ++j) s += wp[j] * (float)hv[j];
        }
    out[id] = s;
}

extern "C" void kernel_launch(void* const* d_in, const int* in_sizes, int n_in,
                              void* d_out, int out_size, void* d_ws, size_t ws_size,
                              hipStream_t stream) {
    const float* x   = (const float*)d_in[0];
    const float* Whx = (const float*)d_in[1];
    const float* Whh = (const float*)d_in[2];
    const float* Wyh = (const float*)d_in[3];
    const float* bh  = (const float*)d_in[4];
    const float* by  = (const float*)d_in[5];
    float* out = (float*)d_out;

    char* ws   = (char*)d_ws;
    f16*  hG   = (f16*)ws;                       // 1 MB
    f16*  frag = (f16*)(ws + (2 << 20));         // 512 KB

    wconv_kernel<<<128, 256, 0, stream>>>(Whh, frag);
    rnn_cu<<<64, 256, 0, stream>>>(frag, hG, x, Whx, bh);
    y_kernel<<<(BATCH * OUTD + 255) / 256, 256, 0, stream>>>(hG, Wyh, by, out);
}

// Round 9
// 2137.120 us; speedup vs baseline: 1.7634x; 1.7634x over previous
//
#include <hip/hip_runtime.h>

// VanillaRNN: BATCH=1024, SEQ=512, HID=512, OUT=10
// h <- tanh(W_hh @ h + W_hx x_t + b_h), 512 steps, then y = W_yh h + b_y.
//
// Round 9: R4 skeleton (64 WGs x 512 thr, 8 waves x 4 M-tiles, 2 waves/SIMD
// -> latency hiding that R8 proved essential) + R8's now-proven "+a" AGPR
// pinning, sized to the 256-reg/lane budget:
//   kk 0..6  (K=224): 28 f16x8 frags/lane pinned to AGPRs (112 regs;
//                     112 + ~124 arch = 236 <= 256 -> no spill)
//   kk 7..10 (K=128): LDS WL (128 KB)
//   kk 11..15(K=160): streamed from L2 each step (160 KB/CU-step = 2500 cyc
//                     at the measured 64 B/cyc/CU; was 384 KB in R4)
// Per-CU-step pipes: L2 2500 / LDS ~2600 / MFMA 2484 cyc - balanced at the
// floor. h (16 KB) in LDS in place, 2 barriers/step. Math identical to
// R3-R8 (absmax 9.77e-4).
//
// ws: [0,1MB) hG (final h, frag-blocked) | [2MB,2.5MB) W A-frags.

#define BATCH 1024
#define SEQT  512
#define HID   512
#define OUTD  10
#define KA    7    // kk-blocks (of K=32) pinned in AGPRs
#define KL    4    // kk-blocks in LDS (kk 7..10); kk 11..15 streamed

typedef _Float16 f16;
typedef _Float16 f16x8 __attribute__((ext_vector_type(8)));
typedef _Float16 f16x4 __attribute__((ext_vector_type(4)));
typedef float    f32x4 __attribute__((ext_vector_type(4)));

// W_hh fp32 [H][H] -> fp16 A-fragment layout:
// entry (G*16+kk)*64+lane = f16x8 of A[m][k],
// m = G*16+(lane&15), k = kk*32+((lane>>4)&3)*8+j.  (G = 16-row tile, 0..31)
__global__ void wconv_kernel(const float* __restrict__ Whh, f16* __restrict__ frag) {
    int id = blockIdx.x * blockDim.x + threadIdx.x;   // 0..32767
    int lane = id & 63;
    int kk   = (id >> 6) & 15;
    int G    = id >> 10;
    int m = G * 16 + (lane & 15);
    int k = kk * 32 + ((lane >> 4) & 3) * 8;
    const float* src = Whh + (size_t)m * HID + k;
    f16x8 v;
#pragma unroll
    for (int j = 0; j < 8; ++j) v[j] = (f16)src[j];
    *(f16x8*)(frag + (size_t)id * 8) = v;
}

__device__ __forceinline__ float fast_tanh(float v) {
    v = fminf(fmaxf(v, -15.f), 15.f);
    float e = __expf(2.f * v);
    return (e - 1.f) * __builtin_amdgcn_rcpf(e + 1.f);
}

__global__ __launch_bounds__(512)
__attribute__((amdgpu_waves_per_eu(2, 2)))
void rnn_cu(
    const f16* __restrict__ frag,   // W_hh A-frags (all 16 kk-blocks)
    f16* __restrict__ hG,           // final h, frag-blocked
    const float* __restrict__ x,    // [B][T]
    const float* __restrict__ Whx,  // [H]
    const float* __restrict__ bh)   // [H]
{
    __shared__ f16 HB[8192];        // h, B-frag layout, 16 KB (low ds offsets)
    __shared__ f16 WL[65536];       // W A-frags kk 7..10, 128 KB

    const int tid  = threadIdx.x;
    const int w    = tid >> 6;      // wave: rows [w*64, +64) = G w*4..w*4+3
    const int lane = tid & 63;
    const int n    = lane & 15;
    const int q    = lane >> 4;
    const int bg   = blockIdx.x;    // batch cols [bg*16, +16)

    // ---- h(0) = 0 ----
    {
        f16x8 z;
#pragma unroll
        for (int j = 0; j < 8; ++j) z[j] = (f16)0.f;
        *(f16x8*)&HB[tid * 16]     = z;
        *(f16x8*)&HB[tid * 16 + 8] = z;
    }

    const f16x8* A = (const f16x8*)frag;

    // ---- stage LDS W (kk 7..10): wave w writes its 4 G-tiles x 4 kk ----
#pragma unroll
    for (int mt = 0; mt < 4; ++mt)
#pragma unroll
        for (int kkl = 0; kkl < KL; ++kkl) {
            int G = w * 4 + mt;
            *(f16x8*)&WL[(size_t)((G * 4 + kkl) * 64 + lane) * 8] =
                A[(size_t)(G * 16 + (KA + kkl)) * 64 + lane];
        }

    // ---- AGPR W (kk 0..6): 28 frags = 112 AGPRs/lane, virtually pinned.
    // "+a" = non-rematerializable AGPR-class def (mechanism validated in R8:
    // WRITE_SIZE stayed 1 MB = no spill). 112 + ~124 arch <= 256 budget.
    f16x8 Wr[KA * 4];
#pragma unroll
    for (int kk = 0; kk < KA; ++kk)
#pragma unroll
        for (int mt = 0; mt < 4; ++mt)
            Wr[kk * 4 + mt] = A[(size_t)((w * 4 + mt) * 16 + kk) * 64 + lane];
#pragma unroll
    for (int i = 0; i < KA * 4; ++i)
        asm volatile("" : "+a"(Wr[i]));

    __syncthreads();

    const int b = bg * 16 + n;
    const float* xp = x + (size_t)b * SEQT;

#pragma unroll 1
    for (int s = 0; s < SEQT; ++s) {
        float xv = xp[s];

        // Laundered stream pointer (keeps per-step loads, blocks hoisting).
        const f16x8* Ap = A;
        asm volatile("" : "+v"(Ap));

        f32x4 acc[4] = {{0,0,0,0},{0,0,0,0},{0,0,0,0},{0,0,0,0}};

        // ---- phase 1: kk 0..6 from AGPRs ----
#pragma unroll
        for (int kk = 0; kk < KA; ++kk) {
            f16x8 bf = *(const f16x8*)&HB[(kk * 64 + lane) * 8];
#pragma unroll
            for (int mt = 0; mt < 4; ++mt)
                acc[mt] = __builtin_amdgcn_mfma_f32_16x16x32_f16(
                    Wr[kk * 4 + mt], bf, acc[mt], 0, 0, 0);
        }

        // ---- phase 2: kk 7..10 from LDS ----
#pragma unroll
        for (int kkl = 0; kkl < KL; ++kkl) {
            f16x8 bf = *(const f16x8*)&HB[((KA + kkl) * 64 + lane) * 8];
#pragma unroll
            for (int mt = 0; mt < 4; ++mt) {
                int G = w * 4 + mt;
                f16x8 a = *(const f16x8*)&WL[(size_t)((G * 4 + kkl) * 64 + lane) * 8];
                acc[mt] = __builtin_amdgcn_mfma_f32_16x16x32_f16(a, bf, acc[mt], 0, 0, 0);
            }
        }

        // ---- phase 3: kk 11..15 streamed from L2 (2 waves/SIMD keep the
        // pipe full - the R4-proven 64 B/cyc/CU regime) ----
#pragma unroll
        for (int kks = KA + KL; kks < 16; ++kks) {
            f16x8 bf = *(const f16x8*)&HB[(kks * 64 + lane) * 8];
#pragma unroll
            for (int mt = 0; mt < 4; ++mt) {
                f16x8 a = Ap[(size_t)((w * 4 + mt) * 16 + kks) * 64 + lane];
                acc[mt] = __builtin_amdgcn_mfma_f32_16x16x32_f16(a, bf, acc[mt], 0, 0, 0);
            }
        }

        __syncthreads();   // all reads of h(s) done before in-place overwrite

        // Keep Whx/bh loads in-loop (hoisting costs 32 regs -> spill risk).
        const float* wbp = Whx;
        const float* bbp = bh;
        asm volatile("" : "+v"(wbp), "+v"(bbp));

        // ---- epilogue: tanh, write h(s+1) in B-frag layout ----
        // C layout: col n = lane&15, row m = G*16 + q*4 + r.
#pragma unroll
        for (int mt = 0; mt < 4; ++mt) {
            int G  = w * 4 + mt;
            int m0 = G * 16 + q * 4;
            f32x4 whx4 = *(const f32x4*)(wbp + m0);
            f32x4 bh4  = *(const f32x4*)(bbp + m0);
            f16x4 hv;
#pragma unroll
            for (int r = 0; r < 4; ++r) {
                float pre = acc[mt][r] + whx4[r] * xv + bh4[r];
                hv[r] = (f16)fast_tanh(pre);
            }
            int kkd = G >> 1;
            int q2  = (G & 1) * 2 + (q >> 1);
            int j0  = (q & 1) * 4;
            int off = (kkd * 64 + q2 * 16 + n) * 8 + j0;
            if (s < SEQT - 1) {
                *(f16x4*)&HB[off] = hv;
            } else {
                *(f16x4*)(hG + (size_t)(((bg * 16 + kkd) * 64 + q2 * 16 + n) * 8 + j0)) = hv;
            }
        }

        __syncthreads();   // h(s+1) complete before next step's reads
    }
}

// out[b][o] = by[o] + sum_k Wyh[o][k] * h[b][k], h in frag-blocked layout.
__global__ __launch_bounds__(256) void y_kernel(
    const f16* __restrict__ h, const float* __restrict__ Wyh,
    const float* __restrict__ by, float* __restrict__ out)
{
    int id = blockIdx.x * blockDim.x + threadIdx.x;
    if (id >= BATCH * OUTD) return;
    int b = id / OUTD, o = id % OUTD;
    int bg = b >> 4, n = b & 15;
    const float* wrow = Wyh + (size_t)o * HID;
    float s = by[o];
    for (int kk = 0; kk < 16; ++kk)
#pragma unroll
        for (int q2 = 0; q2 < 4; ++q2) {
            f16x8 hv = *(const f16x8*)(h + (size_t)((bg * 16 + kk) * 64 + q2 * 16 + n) * 8);
            const float* wp = wrow + kk * 32 + q2 * 8;
#pragma unroll
            for (int j = 0; j < 8; ++j) s += wp[j] * (float)hv[j];
        }
    out[id] = s;
}

extern "C" void kernel_launch(void* const* d_in, const int* in_sizes, int n_in,
                              void* d_out, int out_size, void* d_ws, size_t ws_size,
                              hipStream_t stream) {
    const float* x   = (const float*)d_in[0];
    const float* Whx = (const float*)d_in[1];
    const float* Whh = (const float*)d_in[2];
    const float* Wyh = (const float*)d_in[3];
    const float* bh  = (const float*)d_in[4];
    const float* by  = (const float*)d_in[5];
    float* out = (float*)d_out;

    char* ws   = (char*)d_ws;
    f16*  hG   = (f16*)ws;                       // 1 MB
    f16*  frag = (f16*)(ws + (2 << 20));         // 512 KB

    wconv_kernel<<<128, 256, 0, stream>>>(Whh, frag);
    rnn_cu<<<64, 512, 0, stream>>>(frag, hG, x, Whx, bh);
    y_kernel<<<(BATCH * OUTD + 255) / 256, 256, 0, stream>>>(hG, Wyh, by, out);
}